// Round 1
// baseline (1552.813 us; speedup 1.0000x reference)
//
#include <hip/hip_runtime.h>
#include <hip/hip_fp16.h>

// ConditionalRQSplineCouplingLayer fused kernel, MI355X gfx950.
// Strategy: fp32->fp16 hi/lo split GEMMs on MFMA (3 mfma per K-frag pair,
// ~17 mantissa bits ~= fp32), fully fused 96->512->512->800 MLP + RQ spline.
// M_TILE=32 rows/block, 8 waves, activations in XOR-swizzled LDS planes,
// weights pre-transposed to [n][k] hi/lo f16 planes in d_ws (L2-resident).

typedef _Float16 f16x8 __attribute__((ext_vector_type(8)));
typedef float f32x4 __attribute__((ext_vector_type(4)));

#define MROWS 32
#define XS 104          // x-tile LDS stride (halves), 96 padded
#define NWAVES 8
#define TPB 512

// ws plane offsets in halves (Wt layout: [n][k], hi plane then lo plane)
#define OFF_H1 0
#define OFF_L1 49152
#define OFF_H2 98304
#define OFF_L2 360448
#define OFF_H3 622592
#define OFF_L3 1032192
#define WS_HALVES 1441792

#define SMEM_BYTES 144384

__global__ __launch_bounds__(256) void prep_weights(
    const float* __restrict__ W1, const float* __restrict__ W2,
    const float* __restrict__ W3, _Float16* __restrict__ ws)
{
  int idx = blockIdx.x * 256 + threadIdx.x;
  float v; int hoff, loff;
  if (idx < 49152) {                 // W1t: n in [0,512), k in [0,96)
    int n = idx / 96, k = idx - n * 96;
    v = W1[k * 512 + n];
    hoff = OFF_H1 + idx; loff = OFF_L1 + idx;
  } else if (idx < 311296) {         // W2t: 512x512
    int i = idx - 49152;
    int n = i >> 9, k = i & 511;
    v = W2[k * 512 + n];
    hoff = OFF_H2 + i; loff = OFF_L2 + i;
  } else if (idx < 720896) {         // W3t: 800x512
    int i = idx - 311296;
    int n = i >> 9, k = i & 511;
    v = W3[k * 800 + n];
    hoff = OFF_H3 + i; loff = OFF_L3 + i;
  } else {
    return;
  }
  _Float16 hi = (_Float16)v;
  _Float16 lo = (_Float16)(v - (float)hi);
  ws[hoff] = hi; ws[loff] = lo;
}

__device__ __forceinline__ void mfma3(f32x4& c, f16x8 aH, f16x8 aL, f16x8 bH, f16x8 bL) {
  c = __builtin_amdgcn_mfma_f32_16x16x32_f16(aH, bH, c, 0, 0, 0);
  c = __builtin_amdgcn_mfma_f32_16x16x32_f16(aL, bH, c, 0, 0, 0);
  c = __builtin_amdgcn_mfma_f32_16x16x32_f16(aH, bL, c, 0, 0, 0);
}

// swizzled offset into a [32][512] half plane: row-major, 16B-group XOR by row&7
__device__ __forceinline__ int swz(int row, int col) {
  return row * 512 + ((((col >> 3) ^ (row & 7)) << 3) | (col & 7));
}

__global__ __launch_bounds__(TPB, 2) void fused_flow(
    const float* __restrict__ z, const float* __restrict__ cond,
    const float* __restrict__ b1, const float* __restrict__ b2,
    const float* __restrict__ b3, const _Float16* __restrict__ ws,
    float* __restrict__ out, int B)
{
  extern __shared__ char smem[];
  _Float16* h1H = (_Float16*)(smem);             // 32*512*2 = 32768 B
  _Float16* h1L = (_Float16*)(smem + 32768);
  _Float16* h2H = (_Float16*)(smem + 65536);
  _Float16* h2L = (_Float16*)(smem + 98304);
  _Float16* xH  = (_Float16*)(smem + 131072);    // 32*104*2 = 6656 B
  _Float16* xL  = (_Float16*)(smem + 137728);
  float* pbuf   = (float*)(smem);                // overlay on h1 region: 32*401*4 = 51328 B

  const int tid  = threadIdx.x;
  const int lane = tid & 63;
  const int wave = tid >> 6;
  const int r15  = lane & 15;
  const int g4   = lane >> 4;
  const int row0 = blockIdx.x * MROWS;

  const _Float16* w1H = ws + OFF_H1; const _Float16* w1L = ws + OFF_L1;
  const _Float16* w2H = ws + OFF_H2; const _Float16* w2L = ws + OFF_L2;
  const _Float16* w3H = ws + OFF_H3; const _Float16* w3L = ws + OFF_L3;

  // ---- z1 passthrough (32 rows x 32 cols) ----
  #pragma unroll
  for (int rep = 0; rep < 2; ++rep) {
    int i = tid + rep * TPB;
    int r = i >> 5, c = i & 31;
    out[(row0 + r) * 64 + c] = z[(row0 + r) * 64 + c];
  }

  // ---- stage x = [z1 | cond] as hi/lo f16 (32 x 96) ----
  #pragma unroll
  for (int rep = 0; rep < 6; ++rep) {
    int i = tid + rep * TPB;
    int r = i / 96, c = i - r * 96;
    float v = (c < 32) ? z[(row0 + r) * 64 + c] : cond[(row0 + r) * 64 + (c - 32)];
    _Float16 hi = (_Float16)v;
    xH[r * XS + c] = hi;
    xL[r * XS + c] = (_Float16)(v - (float)hi);
  }
  __syncthreads();

  // ---- GEMM1: (32x96) @ (96x512), K=96 ----
  f32x4 acc[2][4];
  #pragma unroll
  for (int mt = 0; mt < 2; ++mt)
    #pragma unroll
    for (int t = 0; t < 4; ++t)
      acc[mt][t] = (f32x4){0.f, 0.f, 0.f, 0.f};

  #pragma unroll
  for (int ks = 0; ks < 3; ++ks) {
    int kb = ks * 32 + g4 * 8;
    f16x8 a0H = *(const f16x8*)(xH + r15 * XS + kb);
    f16x8 a0L = *(const f16x8*)(xL + r15 * XS + kb);
    f16x8 a1H = *(const f16x8*)(xH + (r15 + 16) * XS + kb);
    f16x8 a1L = *(const f16x8*)(xL + (r15 + 16) * XS + kb);
    #pragma unroll
    for (int t = 0; t < 4; ++t) {
      int ncol = (wave * 4 + t) * 16 + r15;
      f16x8 bH = *(const f16x8*)(w1H + ncol * 96 + kb);
      f16x8 bL = *(const f16x8*)(w1L + ncol * 96 + kb);
      mfma3(acc[0][t], a0H, a0L, bH, bL);
      mfma3(acc[1][t], a1H, a1L, bH, bL);
    }
  }
  // epilogue: bias + relu + hi/lo -> h1 planes (swizzled)
  #pragma unroll
  for (int t = 0; t < 4; ++t) {
    int ncol = (wave * 4 + t) * 16 + r15;
    float bias = b1[ncol];
    #pragma unroll
    for (int mt = 0; mt < 2; ++mt)
      #pragma unroll
      for (int i = 0; i < 4; ++i) {
        int row = mt * 16 + g4 * 4 + i;
        float v = fmaxf(acc[mt][t][i] + bias, 0.f);
        _Float16 hi = (_Float16)v;
        int off = swz(row, ncol);
        h1H[off] = hi;
        h1L[off] = (_Float16)(v - (float)hi);
      }
  }
  __syncthreads();

  // ---- GEMM2: (32x512) @ (512x512), K=512 ----
  #pragma unroll
  for (int mt = 0; mt < 2; ++mt)
    #pragma unroll
    for (int t = 0; t < 4; ++t)
      acc[mt][t] = (f32x4){0.f, 0.f, 0.f, 0.f};

  for (int ks = 0; ks < 16; ++ks) {
    int kb = ks * 32 + g4 * 8;
    int g = kb >> 3;
    int o0 = r15 * 512 + (((g ^ (r15 & 7)) << 3));
    int o1 = (r15 + 16) * 512 + (((g ^ (r15 & 7)) << 3));
    f16x8 a0H = *(const f16x8*)(h1H + o0);
    f16x8 a0L = *(const f16x8*)(h1L + o0);
    f16x8 a1H = *(const f16x8*)(h1H + o1);
    f16x8 a1L = *(const f16x8*)(h1L + o1);
    #pragma unroll
    for (int t = 0; t < 4; ++t) {
      int ncol = (wave * 4 + t) * 16 + r15;
      f16x8 bH = *(const f16x8*)(w2H + ncol * 512 + kb);
      f16x8 bL = *(const f16x8*)(w2L + ncol * 512 + kb);
      mfma3(acc[0][t], a0H, a0L, bH, bL);
      mfma3(acc[1][t], a1H, a1L, bH, bL);
    }
  }
  #pragma unroll
  for (int t = 0; t < 4; ++t) {
    int ncol = (wave * 4 + t) * 16 + r15;
    float bias = b2[ncol];
    #pragma unroll
    for (int mt = 0; mt < 2; ++mt)
      #pragma unroll
      for (int i = 0; i < 4; ++i) {
        int row = mt * 16 + g4 * 4 + i;
        float v = fmaxf(acc[mt][t][i] + bias, 0.f);
        _Float16 hi = (_Float16)v;
        int off = swz(row, ncol);
        h2H[off] = hi;
        h2L[off] = (_Float16)(v - (float)hi);
      }
  }
  __syncthreads();

  // ---- GEMM3: (32x512) @ (512x800), K=512, 50 n-tiles cyclic over 8 waves ----
  f32x4 acc3[2][7];
  #pragma unroll
  for (int mt = 0; mt < 2; ++mt)
    #pragma unroll
    for (int tt = 0; tt < 7; ++tt)
      acc3[mt][tt] = (f32x4){0.f, 0.f, 0.f, 0.f};

  for (int ks = 0; ks < 16; ++ks) {
    int kb = ks * 32 + g4 * 8;
    int g = kb >> 3;
    int o0 = r15 * 512 + (((g ^ (r15 & 7)) << 3));
    int o1 = (r15 + 16) * 512 + (((g ^ (r15 & 7)) << 3));
    f16x8 a0H = *(const f16x8*)(h2H + o0);
    f16x8 a0L = *(const f16x8*)(h2L + o0);
    f16x8 a1H = *(const f16x8*)(h2H + o1);
    f16x8 a1L = *(const f16x8*)(h2L + o1);
    #pragma unroll
    for (int tt = 0; tt < 7; ++tt) {
      int nt = wave + tt * 8;
      if (nt < 50) {  // wave-uniform
        int ncol = nt * 16 + r15;
        f16x8 bH = *(const f16x8*)(w3H + ncol * 512 + kb);
        f16x8 bL = *(const f16x8*)(w3L + ncol * 512 + kb);
        mfma3(acc3[0][tt], a0H, a0L, bH, bL);
        mfma3(acc3[1][tt], a1H, a1L, bH, bL);
      }
    }
  }

  // ---- spline epilogue in two 16-dim chunks (params overlay h1 region) ----
  float logdet_part = 0.f;
  const int sr  = tid >> 4;   // row 0..31
  const int sdl = tid & 15;   // dim-local 0..15

  #pragma unroll 1
  for (int c = 0; c < 2; ++c) {
    __syncthreads();
    // write this chunk's params (cols c*400 .. c*400+399) + b3 to pbuf
    #pragma unroll
    for (int tt = 0; tt < 7; ++tt) {
      int nt = wave + tt * 8;
      if (nt >= c * 25 && nt < c * 25 + 25) {
        int ncolg = nt * 16 + r15;
        int ncoll = ncolg - c * 400;
        float bias = b3[ncolg];
        #pragma unroll
        for (int mt = 0; mt < 2; ++mt)
          #pragma unroll
          for (int i = 0; i < 4; ++i) {
            int row = mt * 16 + g4 * 4 + i;
            pbuf[row * 401 + ncoll] = acc3[mt][tt][i] + bias;
          }
      }
    }
    __syncthreads();

    // one (row, dim) spline per thread
    {
      int dim = c * 16 + sdl;
      float p[25];
      #pragma unroll
      for (int j = 0; j < 25; ++j) p[j] = pbuf[sr * 401 + sdl * 25 + j];

      float cw[9], ch[9], dv[9];
      {
        float m = p[0];
        #pragma unroll
        for (int j = 1; j < 8; ++j) m = fmaxf(m, p[j]);
        float e[8]; float s = 0.f;
        #pragma unroll
        for (int j = 0; j < 8; ++j) { e[j] = __expf(p[j] - m); s += e[j]; }
        float inv = 5.992f / s;
        cw[0] = -3.f; float a = 0.f;
        #pragma unroll
        for (int j = 0; j < 8; ++j) { a += e[j] * inv + 0.001f; cw[j + 1] = a - 3.f; }
      }
      {
        float m = p[8];
        #pragma unroll
        for (int j = 1; j < 8; ++j) m = fmaxf(m, p[8 + j]);
        float e[8]; float s = 0.f;
        #pragma unroll
        for (int j = 0; j < 8; ++j) { e[j] = __expf(p[8 + j] - m); s += e[j]; }
        float inv = 5.992f / s;
        ch[0] = -3.f; float a = 0.f;
        #pragma unroll
        for (int j = 0; j < 8; ++j) { a += e[j] * inv + 0.001f; ch[j + 1] = a - 3.f; }
      }
      #pragma unroll
      for (int j = 0; j < 9; ++j) {
        float t = p[16 + j];
        float sp = fmaxf(t, 0.f) + log1pf(__expf(-fabsf(t)));
        dv[j] = fminf(sp + 0.001f, 10.f);
      }

      float xin = z[(row0 + sr) * 64 + 32 + dim];
      bool inside = (xin >= -3.f) && (xin <= 3.f);
      float xc = fminf(fmaxf(xin, -3.f), 3.f);
      int b = 0;
      #pragma unroll
      for (int j = 1; j <= 8; ++j) b += (xc >= cw[j]) ? 1 : 0;
      if (b > 7) b = 7;

      float icw = cw[0], icw1 = cw[1], och = ch[0], och1 = ch[1], dl0 = dv[0], dr0 = dv[1];
      #pragma unroll
      for (int j = 1; j < 8; ++j) {
        bool sel = (b == j);
        icw  = sel ? cw[j]     : icw;
        icw1 = sel ? cw[j + 1] : icw1;
        och  = sel ? ch[j]     : och;
        och1 = sel ? ch[j + 1] : och1;
        dl0  = sel ? dv[j]     : dl0;
        dr0  = sel ? dv[j + 1] : dr0;
      }
      float ibw   = fmaxf(icw1 - icw, 1e-6f);
      float obh   = och1 - och;
      float delta = obh / ibw;
      float th    = (xc - icw) / ibw;
      float om    = 1.f - th;
      float tomt  = th * om;
      float numer = obh * (delta * th * th + dl0 * tomt);
      float denom = fmaxf(delta + (dl0 + dr0 - 2.f * delta) * tomt, 1e-6f);
      float outi  = och + numer / denom;
      float dn    = delta * delta * (dr0 * th * th + 2.f * delta * tomt + dl0 * om * om);
      float dd    = denom * denom;
      dn = fmaxf(dn, 1e-6f); dd = fmaxf(dd, 1e-6f);
      float lad   = __logf(dn) - __logf(dd) - __logf(ibw);

      float outv = inside ? outi : xin;
      float ladv = inside ? lad : 0.f;

      out[(row0 + sr) * 64 + 32 + dim] = outv;

      float s = ladv;
      s += __shfl_xor(s, 1);
      s += __shfl_xor(s, 2);
      s += __shfl_xor(s, 4);
      s += __shfl_xor(s, 8);
      if (sdl == 0) logdet_part += s;
    }
  }
  if (sdl == 0) out[(size_t)B * 64 + row0 + sr] = logdet_part;
}

extern "C" void kernel_launch(void* const* d_in, const int* in_sizes, int n_in,
                              void* d_out, int out_size, void* d_ws, size_t ws_size,
                              hipStream_t stream) {
  const float* z    = (const float*)d_in[0];
  const float* cnd  = (const float*)d_in[1];
  const float* W1   = (const float*)d_in[2];
  const float* b1   = (const float*)d_in[3];
  const float* W2   = (const float*)d_in[4];
  const float* b2   = (const float*)d_in[5];
  const float* W3   = (const float*)d_in[6];
  const float* b3   = (const float*)d_in[7];
  float* out        = (float*)d_out;
  _Float16* ws      = (_Float16*)d_ws;

  int B = in_sizes[0] / 64;

  hipFuncSetAttribute((const void*)fused_flow,
                      hipFuncAttributeMaxDynamicSharedMemorySize, SMEM_BYTES);

  prep_weights<<<(720896 + 255) / 256, 256, 0, stream>>>(W1, W2, W3, ws);
  fused_flow<<<B / MROWS, TPB, SMEM_BYTES, stream>>>(z, cnd, b1, b2, b3, ws, out, B);
}

// Round 3
// 1463.651 us; speedup vs baseline: 1.0609x; 1.0609x over previous
//
#include <hip/hip_runtime.h>
#include <hip/hip_fp16.h>

// ConditionalRQSplineCouplingLayer fused kernel, MI355X gfx950.
// R3 = R2 resubmitted (R2 bench failed on GPU acquisition, no data).
// Single shared hi/lo LDS activation buffer (h1 and h2 reuse it; GEMM2
// output lives in registers across the swap) -> LDS 144KB -> 77KB -> 2
// blocks/CU (4 waves/SIMD) to fix the diagnosed latency-bound stall
// (R1: MfmaUtil 15%, VALUBusy 20%, Occupancy 23.5%, HBM 1%).
// Precision scheme unchanged: fp32->fp16 hi/lo split, 3 mfma per K-frag.

typedef _Float16 f16x8 __attribute__((ext_vector_type(8)));
typedef float f32x4 __attribute__((ext_vector_type(4)));

#define MROWS 32
#define XS 104          // x-tile LDS stride (halves), 96 padded
#define TPB 512

// ws plane offsets in halves (Wt layout: [n][k], hi plane then lo plane)
#define OFF_H1 0
#define OFF_L1 49152
#define OFF_H2 98304
#define OFF_L2 360448
#define OFF_H3 622592
#define OFF_L3 1032192

// LDS: hbH 32*512*2=32768 | hbL 32768 | xH 6656 | xL 6656  => 78848 B
#define SMEM_BYTES 78848

__global__ __launch_bounds__(256) void prep_weights(
    const float* __restrict__ W1, const float* __restrict__ W2,
    const float* __restrict__ W3, _Float16* __restrict__ ws)
{
  int idx = blockIdx.x * 256 + threadIdx.x;
  float v; int hoff, loff;
  if (idx < 49152) {                 // W1t: n in [0,512), k in [0,96)
    int n = idx / 96, k = idx - n * 96;
    v = W1[k * 512 + n];
    hoff = OFF_H1 + idx; loff = OFF_L1 + idx;
  } else if (idx < 311296) {         // W2t: 512x512
    int i = idx - 49152;
    int n = i >> 9, k = i & 511;
    v = W2[k * 512 + n];
    hoff = OFF_H2 + i; loff = OFF_L2 + i;
  } else if (idx < 720896) {         // W3t: 800x512
    int i = idx - 311296;
    int n = i >> 9, k = i & 511;
    v = W3[k * 800 + n];
    hoff = OFF_H3 + i; loff = OFF_L3 + i;
  } else {
    return;
  }
  _Float16 hi = (_Float16)v;
  _Float16 lo = (_Float16)(v - (float)hi);
  ws[hoff] = hi; ws[loff] = lo;
}

__device__ __forceinline__ void mfma3(f32x4& c, f16x8 aH, f16x8 aL, f16x8 bH, f16x8 bL) {
  c = __builtin_amdgcn_mfma_f32_16x16x32_f16(aH, bH, c, 0, 0, 0);
  c = __builtin_amdgcn_mfma_f32_16x16x32_f16(aL, bH, c, 0, 0, 0);
  c = __builtin_amdgcn_mfma_f32_16x16x32_f16(aH, bL, c, 0, 0, 0);
}

// swizzled offset into a [32][512] half plane: row-major, 16B-group XOR by row&7
__device__ __forceinline__ int swz(int row, int col) {
  return row * 512 + ((((col >> 3) ^ (row & 7)) << 3) | (col & 7));
}

__global__ __launch_bounds__(TPB, 4) void fused_flow(
    const float* __restrict__ z, const float* __restrict__ cond,
    const float* __restrict__ b1, const float* __restrict__ b2,
    const float* __restrict__ b3, const _Float16* __restrict__ ws,
    float* __restrict__ out, int B)
{
  extern __shared__ char smem[];
  _Float16* hbH = (_Float16*)(smem);             // 32*512*2 = 32768 B (h1, then h2)
  _Float16* hbL = (_Float16*)(smem + 32768);
  _Float16* xH  = (_Float16*)(smem + 65536);     // 32*104*2 = 6656 B
  _Float16* xL  = (_Float16*)(smem + 72192);
  float* pbuf   = (float*)(smem);                // overlay on hb region: 32*401*4 = 51328 B

  const int tid  = threadIdx.x;
  const int lane = tid & 63;
  const int wave = tid >> 6;
  const int r15  = lane & 15;
  const int g4   = lane >> 4;
  const int row0 = blockIdx.x * MROWS;

  const _Float16* w1H = ws + OFF_H1; const _Float16* w1L = ws + OFF_L1;
  const _Float16* w2H = ws + OFF_H2; const _Float16* w2L = ws + OFF_L2;
  const _Float16* w3H = ws + OFF_H3; const _Float16* w3L = ws + OFF_L3;

  // ---- z1 passthrough (32 rows x 32 cols) ----
  #pragma unroll
  for (int rep = 0; rep < 2; ++rep) {
    int i = tid + rep * TPB;
    int r = i >> 5, c = i & 31;
    out[(row0 + r) * 64 + c] = z[(row0 + r) * 64 + c];
  }

  // ---- stage x = [z1 | cond] as hi/lo f16 (32 x 96) ----
  #pragma unroll
  for (int rep = 0; rep < 6; ++rep) {
    int i = tid + rep * TPB;
    int r = i / 96, c = i - r * 96;
    float v = (c < 32) ? z[(row0 + r) * 64 + c] : cond[(row0 + r) * 64 + (c - 32)];
    _Float16 hi = (_Float16)v;
    xH[r * XS + c] = hi;
    xL[r * XS + c] = (_Float16)(v - (float)hi);
  }
  __syncthreads();

  // ---- GEMM1: (32x96) @ (96x512), K=96 ----
  f32x4 acc[2][4];
  #pragma unroll
  for (int mt = 0; mt < 2; ++mt)
    #pragma unroll
    for (int t = 0; t < 4; ++t)
      acc[mt][t] = (f32x4){0.f, 0.f, 0.f, 0.f};

  #pragma unroll
  for (int ks = 0; ks < 3; ++ks) {
    int kb = ks * 32 + g4 * 8;
    f16x8 a0H = *(const f16x8*)(xH + r15 * XS + kb);
    f16x8 a0L = *(const f16x8*)(xL + r15 * XS + kb);
    f16x8 a1H = *(const f16x8*)(xH + (r15 + 16) * XS + kb);
    f16x8 a1L = *(const f16x8*)(xL + (r15 + 16) * XS + kb);
    #pragma unroll
    for (int t = 0; t < 4; ++t) {
      int ncol = (wave * 4 + t) * 16 + r15;
      f16x8 bH = *(const f16x8*)(w1H + ncol * 96 + kb);
      f16x8 bL = *(const f16x8*)(w1L + ncol * 96 + kb);
      mfma3(acc[0][t], a0H, a0L, bH, bL);
      mfma3(acc[1][t], a1H, a1L, bH, bL);
    }
  }
  // epilogue: bias + relu + hi/lo -> hb planes (h1, swizzled)
  #pragma unroll
  for (int t = 0; t < 4; ++t) {
    int ncol = (wave * 4 + t) * 16 + r15;
    float bias = b1[ncol];
    #pragma unroll
    for (int mt = 0; mt < 2; ++mt)
      #pragma unroll
      for (int i = 0; i < 4; ++i) {
        int row = mt * 16 + g4 * 4 + i;
        float v = fmaxf(acc[mt][t][i] + bias, 0.f);
        _Float16 hi = (_Float16)v;
        int off = swz(row, ncol);
        hbH[off] = hi;
        hbL[off] = (_Float16)(v - (float)hi);
      }
  }
  __syncthreads();

  // ---- GEMM2: (32x512) @ (512x512), K=512, output held in registers ----
  #pragma unroll
  for (int mt = 0; mt < 2; ++mt)
    #pragma unroll
    for (int t = 0; t < 4; ++t)
      acc[mt][t] = (f32x4){0.f, 0.f, 0.f, 0.f};

  for (int ks = 0; ks < 16; ++ks) {
    int kb = ks * 32 + g4 * 8;
    int g = kb >> 3;
    int o0 = r15 * 512 + (((g ^ (r15 & 7)) << 3));
    int o1 = (r15 + 16) * 512 + (((g ^ (r15 & 7)) << 3));
    f16x8 a0H = *(const f16x8*)(hbH + o0);
    f16x8 a0L = *(const f16x8*)(hbL + o0);
    f16x8 a1H = *(const f16x8*)(hbH + o1);
    f16x8 a1L = *(const f16x8*)(hbL + o1);
    #pragma unroll
    for (int t = 0; t < 4; ++t) {
      int ncol = (wave * 4 + t) * 16 + r15;
      f16x8 bH = *(const f16x8*)(w2H + ncol * 512 + kb);
      f16x8 bL = *(const f16x8*)(w2L + ncol * 512 + kb);
      mfma3(acc[0][t], a0H, a0L, bH, bL);
      mfma3(acc[1][t], a1H, a1L, bH, bL);
    }
  }
  // all h1 reads complete before overwriting the shared buffer with h2
  __syncthreads();
  #pragma unroll
  for (int t = 0; t < 4; ++t) {
    int ncol = (wave * 4 + t) * 16 + r15;
    float bias = b2[ncol];
    #pragma unroll
    for (int mt = 0; mt < 2; ++mt)
      #pragma unroll
      for (int i = 0; i < 4; ++i) {
        int row = mt * 16 + g4 * 4 + i;
        float v = fmaxf(acc[mt][t][i] + bias, 0.f);
        _Float16 hi = (_Float16)v;
        int off = swz(row, ncol);
        hbH[off] = hi;
        hbL[off] = (_Float16)(v - (float)hi);
      }
  }
  __syncthreads();

  // ---- GEMM3: (32x512) @ (512x800), K=512, 50 n-tiles cyclic over 8 waves ----
  f32x4 acc3[2][7];
  #pragma unroll
  for (int mt = 0; mt < 2; ++mt)
    #pragma unroll
    for (int tt = 0; tt < 7; ++tt)
      acc3[mt][tt] = (f32x4){0.f, 0.f, 0.f, 0.f};

  for (int ks = 0; ks < 16; ++ks) {
    int kb = ks * 32 + g4 * 8;
    int g = kb >> 3;
    int o0 = r15 * 512 + (((g ^ (r15 & 7)) << 3));
    int o1 = (r15 + 16) * 512 + (((g ^ (r15 & 7)) << 3));
    f16x8 a0H = *(const f16x8*)(hbH + o0);
    f16x8 a0L = *(const f16x8*)(hbL + o0);
    f16x8 a1H = *(const f16x8*)(hbH + o1);
    f16x8 a1L = *(const f16x8*)(hbL + o1);
    #pragma unroll
    for (int tt = 0; tt < 7; ++tt) {
      int nt = wave + tt * 8;
      if (nt < 50) {  // wave-uniform
        int ncol = nt * 16 + r15;
        f16x8 bH = *(const f16x8*)(w3H + ncol * 512 + kb);
        f16x8 bL = *(const f16x8*)(w3L + ncol * 512 + kb);
        mfma3(acc3[0][tt], a0H, a0L, bH, bL);
        mfma3(acc3[1][tt], a1H, a1L, bH, bL);
      }
    }
  }

  // ---- spline epilogue in two 16-dim chunks (params overlay hb region) ----
  float logdet_part = 0.f;
  const int sr  = tid >> 4;   // row 0..31
  const int sdl = tid & 15;   // dim-local 0..15

  #pragma unroll 1
  for (int c = 0; c < 2; ++c) {
    __syncthreads();  // c=0: GEMM3 reads done; c=1: prev chunk's pbuf reads done
    // write this chunk's params (cols c*400 .. c*400+399) + b3 to pbuf
    #pragma unroll
    for (int tt = 0; tt < 7; ++tt) {
      int nt = wave + tt * 8;
      if (nt >= c * 25 && nt < c * 25 + 25) {
        int ncolg = nt * 16 + r15;
        int ncoll = ncolg - c * 400;
        float bias = b3[ncolg];
        #pragma unroll
        for (int mt = 0; mt < 2; ++mt)
          #pragma unroll
          for (int i = 0; i < 4; ++i) {
            int row = mt * 16 + g4 * 4 + i;
            pbuf[row * 401 + ncoll] = acc3[mt][tt][i] + bias;
          }
      }
    }
    __syncthreads();

    // one (row, dim) spline per thread
    {
      int dim = c * 16 + sdl;
      float p[25];
      #pragma unroll
      for (int j = 0; j < 25; ++j) p[j] = pbuf[sr * 401 + sdl * 25 + j];

      float cw[9], ch[9], dv[9];
      {
        float m = p[0];
        #pragma unroll
        for (int j = 1; j < 8; ++j) m = fmaxf(m, p[j]);
        float e[8]; float s = 0.f;
        #pragma unroll
        for (int j = 0; j < 8; ++j) { e[j] = __expf(p[j] - m); s += e[j]; }
        float inv = 5.992f / s;
        cw[0] = -3.f; float a = 0.f;
        #pragma unroll
        for (int j = 0; j < 8; ++j) { a += e[j] * inv + 0.001f; cw[j + 1] = a - 3.f; }
      }
      {
        float m = p[8];
        #pragma unroll
        for (int j = 1; j < 8; ++j) m = fmaxf(m, p[8 + j]);
        float e[8]; float s = 0.f;
        #pragma unroll
        for (int j = 0; j < 8; ++j) { e[j] = __expf(p[8 + j] - m); s += e[j]; }
        float inv = 5.992f / s;
        ch[0] = -3.f; float a = 0.f;
        #pragma unroll
        for (int j = 0; j < 8; ++j) { a += e[j] * inv + 0.001f; ch[j + 1] = a - 3.f; }
      }
      #pragma unroll
      for (int j = 0; j < 9; ++j) {
        float t = p[16 + j];
        float sp = fmaxf(t, 0.f) + log1pf(__expf(-fabsf(t)));
        dv[j] = fminf(sp + 0.001f, 10.f);
      }

      float xin = z[(row0 + sr) * 64 + 32 + dim];
      bool inside = (xin >= -3.f) && (xin <= 3.f);
      float xc = fminf(fmaxf(xin, -3.f), 3.f);
      int b = 0;
      #pragma unroll
      for (int j = 1; j <= 8; ++j) b += (xc >= cw[j]) ? 1 : 0;
      if (b > 7) b = 7;

      float icw = cw[0], icw1 = cw[1], och = ch[0], och1 = ch[1], dl0 = dv[0], dr0 = dv[1];
      #pragma unroll
      for (int j = 1; j < 8; ++j) {
        bool sel = (b == j);
        icw  = sel ? cw[j]     : icw;
        icw1 = sel ? cw[j + 1] : icw1;
        och  = sel ? ch[j]     : och;
        och1 = sel ? ch[j + 1] : och1;
        dl0  = sel ? dv[j]     : dl0;
        dr0  = sel ? dv[j + 1] : dr0;
      }
      float ibw   = fmaxf(icw1 - icw, 1e-6f);
      float obh   = och1 - och;
      float delta = obh / ibw;
      float th    = (xc - icw) / ibw;
      float om    = 1.f - th;
      float tomt  = th * om;
      float numer = obh * (delta * th * th + dl0 * tomt);
      float denom = fmaxf(delta + (dl0 + dr0 - 2.f * delta) * tomt, 1e-6f);
      float outi  = och + numer / denom;
      float dn    = delta * delta * (dr0 * th * th + 2.f * delta * tomt + dl0 * om * om);
      float dd    = denom * denom;
      dn = fmaxf(dn, 1e-6f); dd = fmaxf(dd, 1e-6f);
      float lad   = __logf(dn) - __logf(dd) - __logf(ibw);

      float outv = inside ? outi : xin;
      float ladv = inside ? lad : 0.f;

      out[(row0 + sr) * 64 + 32 + dim] = outv;

      float s = ladv;
      s += __shfl_xor(s, 1);
      s += __shfl_xor(s, 2);
      s += __shfl_xor(s, 4);
      s += __shfl_xor(s, 8);
      if (sdl == 0) logdet_part += s;
    }
  }
  if (sdl == 0) out[(size_t)B * 64 + row0 + sr] = logdet_part;
}

extern "C" void kernel_launch(void* const* d_in, const int* in_sizes, int n_in,
                              void* d_out, int out_size, void* d_ws, size_t ws_size,
                              hipStream_t stream) {
  const float* z    = (const float*)d_in[0];
  const float* cnd  = (const float*)d_in[1];
  const float* W1   = (const float*)d_in[2];
  const float* b1   = (const float*)d_in[3];
  const float* W2   = (const float*)d_in[4];
  const float* b2   = (const float*)d_in[5];
  const float* W3   = (const float*)d_in[6];
  const float* b3   = (const float*)d_in[7];
  float* out        = (float*)d_out;
  _Float16* ws      = (_Float16*)d_ws;

  int B = in_sizes[0] / 64;

  hipFuncSetAttribute((const void*)fused_flow,
                      hipFuncAttributeMaxDynamicSharedMemorySize, SMEM_BYTES);

  prep_weights<<<(720896 + 255) / 256, 256, 0, stream>>>(W1, W2, W3, ws);
  fused_flow<<<B / MROWS, TPB, SMEM_BYTES, stream>>>(z, cnd, b1, b2, b3, ws, out, B);
}